// Round 7
// baseline (379.728 us; speedup 1.0000x reference)
//
#include <hip/hip_runtime.h>
#include <hip/hip_bf16.h>
#include <math.h>

#define B_   32
#define L_   512
#define C_   862
#define P_   720
#define H2_  1024
#define M_   (B_*C_)     // 27584 = 64 * 431 exactly
#define PP_  768

typedef __hip_bfloat16 bf16;
typedef __attribute__((ext_vector_type(8))) short s16x8;
typedef __attribute__((ext_vector_type(4))) float f32x4;

__device__ __forceinline__ void gload_lds16(const bf16* g, bf16* lds) {
    __builtin_amdgcn_global_load_lds(
        (const __attribute__((address_space(1))) void*)g,
        (__attribute__((address_space(3))) void*)lds, 16, 0, 0);
}
__device__ __forceinline__ unsigned short f2b(float f) {
    bf16 h = __float2bfloat16(f);
    return *reinterpret_cast<unsigned short*>(&h);
}

// ---------------------------------------------------------------- DCT matrix (bf16)
__global__ __launch_bounds__(256) void build_dct(bf16* __restrict__ D) {
    int idx = blockIdx.x * 256 + threadIdx.x;
    if (idx >= L_ * L_) return;
    int k = idx >> 9, l = idx & 511;
    double ang = M_PI * (double)((2 * l + 1) * k) / (2.0 * (double)L_);
    D[idx] = __float2bfloat16((float)(2.0 * cos(ang)));
}

__global__ __launch_bounds__(256) void cvt_bf16(const float* __restrict__ in,
                                                bf16* __restrict__ out, int n) {
    int i = blockIdx.x * 256 + threadIdx.x;
    if (i < n) out[i] = __float2bfloat16(in[i]);
}

// Wl (720,512) -> bf16 padded to (768,512) with zeros
__global__ __launch_bounds__(256) void cvt_wl_pad(const float* __restrict__ in,
                                                  bf16* __restrict__ out) {
    int i = blockIdx.x * 256 + threadIdx.x;
    if (i >= PP_ * L_) return;
    int r = i >> 9;
    out[i] = (r < P_) ? __float2bfloat16(in[i]) : __float2bfloat16(0.f);
}

// ---------------------------------------------------- x (B,L,C) -> Xc (B*C,L) bf16
__global__ __launch_bounds__(256) void transpose_x(const float* __restrict__ x,
                                                   bf16* __restrict__ Xc) {
    __shared__ float tile[32][33];
    int b  = blockIdx.z;
    int c0 = blockIdx.x * 32;
    int l0 = blockIdx.y * 32;
    int tx = threadIdx.x & 31, ty = threadIdx.x >> 5;
#pragma unroll
    for (int i = 0; i < 4; ++i) {
        int l = l0 + ty + i * 8, c = c0 + tx;
        float v = 0.f;
        if (l < L_ && c < C_) v = x[((size_t)b * L_ + l) * C_ + c];
        tile[ty + i * 8][tx] = v;
    }
    __syncthreads();
#pragma unroll
    for (int i = 0; i < 4; ++i) {
        int c = c0 + ty + i * 8, l = l0 + tx;
        if (c < C_ && l < L_)
            Xc[((size_t)b * C_ + c) * L_ + l] = __float2bfloat16(tile[tx][ty + i * 8]);
    }
}

// ----------------------------------------------------------------- fused megakernel
// Block = 64 rows of the flat (b,c) dimension, 8 waves.
// Per-stage GEMM: A (64 rows, k=512) from swizzled LDS; B (weights) streamed from
// global per k-step (L2-resident, 3.25 MB total); acc layout (verified rounds 2-6):
// m = i*16 + fq*4 + r (fq = lane>>4), n = wavecol + j*16 + fr (fr = lane&15).
// LDS swizzle: 16B granule g of row stored at slot g ^ (row&7); ACT filled by
// global_load_lds with inverse-swizzled SOURCE (linear dest, rule #21).

// A from LDS (swizzled), B rows from global. K=512 (16 t-steps).
template <int NJ>
__device__ __forceinline__ void gemm_AB(const bf16 (*Ab)[L_],
                                        const bf16* __restrict__ Bg, int brow0,
                                        size_t brow_bytes, size_t koff_bytes,
                                        int fr, int kq, f32x4 (&acc)[4][NJ]) {
    const char* Bbase = (const char*)Bg + koff_bytes + (size_t)kq * 16;
#pragma unroll
    for (int t = 0; t < 16; ++t) {
        s16x8 bv[NJ];
#pragma unroll
        for (int j = 0; j < NJ; ++j)
            bv[j] = *reinterpret_cast<const s16x8*>(
                Bbase + (size_t)(brow0 + j * 16 + fr) * brow_bytes + t * 64);
        s16x8 av[4];
#pragma unroll
        for (int i = 0; i < 4; ++i) {
            int rowa = i * 16 + fr;
            int slot = ((t << 2) + kq) ^ (rowa & 7);
            av[i] = *reinterpret_cast<const s16x8*>(
                (const char*)Ab + rowa * 1024 + (slot << 4));
        }
#pragma unroll
        for (int i = 0; i < 4; ++i)
#pragma unroll
            for (int j = 0; j < NJ; ++j)
                acc[i][j] = __builtin_amdgcn_mfma_f32_16x16x32_bf16(av[i], bv[j], acc[i][j], 0, 0, 0);
    }
}

__device__ __forceinline__ void swz_st(bf16 (*buf)[L_], int row, int col, float v) {
    int slot = (col >> 3) ^ (row & 7);
    ((unsigned short*)((char*)buf + row * 1024 + (slot << 4)))[col & 7] = f2b(v);
}

__global__ __launch_bounds__(512, 2)
void fused(const bf16* __restrict__ Xc, const bf16* __restrict__ Dm,
           const bf16* __restrict__ W1, const bf16* __restrict__ W2,
           const bf16* __restrict__ Wl, const float* __restrict__ gamma,
           const float* __restrict__ beta, const float* __restrict__ bl,
           float* __restrict__ out) {
    __shared__ __align__(16) bf16 ACT[64][L_];   // Xc tile -> Fn -> Prod
    __shared__ __align__(16) bf16 HB[64][L_];    // H half-chunks
    __shared__ float s_sum[64][8], s_sq[64][8];
    __shared__ float s_mu[64], s_rs[64];

    int tid = threadIdx.x, w = tid >> 6, lane = tid & 63;
    int fr = lane & 15, fq = lane >> 4;
    int row0 = blockIdx.x * 64;

    // ---- S0: stage Xc rows into ACT (linear dest, inverse-swizzled source)
    {
        const char* Gb = (const char*)(Xc + (size_t)row0 * L_);
        int rr = w * 8;
#pragma unroll
        for (int q = 0; q < 8; ++q) {
            int r = rr + q;
            gload_lds16((const bf16*)(Gb + (size_t)r * 1024 + ((lane ^ (r & 7)) << 4)),
                        &ACT[r][0]);
        }
    }
    __syncthreads();

    // ---- S1: freq = ACT . D^T   (wave w owns cols w*64..w*64+63)
    f32x4 facc[4][4] = {};
    gemm_AB<4>(ACT, Dm, w * 64, 1024, 0, fr, fq, facc);

    // gamma/beta for this wave's 4 cols
    float g4[4], b4[4];
#pragma unroll
    for (int j = 0; j < 4; ++j) {
        int n = w * 64 + j * 16 + fr;
        g4[j] = gamma[n]; b4[j] = beta[n];
    }

    // ---- LN reduce helper (acc -> s_mu/s_rs), executed uniformly
    auto ln_reduce = [&](f32x4 (&a)[4][4]) {
        float ps[4][4], pq[4][4];
#pragma unroll
        for (int i = 0; i < 4; ++i)
#pragma unroll
            for (int r = 0; r < 4; ++r) {
                float s = 0.f, q = 0.f;
#pragma unroll
                for (int j = 0; j < 4; ++j) { float v = a[i][j][r]; s += v; q += v * v; }
                ps[i][r] = s; pq[i][r] = q;
            }
#pragma unroll
        for (int msk = 1; msk < 16; msk <<= 1)
#pragma unroll
            for (int i = 0; i < 4; ++i)
#pragma unroll
                for (int r = 0; r < 4; ++r) {
                    ps[i][r] += __shfl_xor(ps[i][r], msk);
                    pq[i][r] += __shfl_xor(pq[i][r], msk);
                }
        if (fr == 0) {
#pragma unroll
            for (int i = 0; i < 4; ++i)
#pragma unroll
                for (int r = 0; r < 4; ++r) {
                    int m = i * 16 + fq * 4 + r;
                    s_sum[m][w] = ps[i][r]; s_sq[m][w] = pq[i][r];
                }
        }
        __syncthreads();
        if (tid < 64) {
            float S = 0.f, Q = 0.f;
#pragma unroll
            for (int k = 0; k < 8; ++k) { S += s_sum[tid][k]; Q += s_sq[tid][k]; }
            float mu = S * (1.f / L_);
            float var = Q * (1.f / L_) - mu * mu;
            s_mu[tid] = mu; s_rs[tid] = rsqrtf(var + 1e-6f);
        }
        __syncthreads();
    };

    // ---- S2: LN(freq) -> Fn into ACT (overwrite; S1 reads complete)
    ln_reduce(facc);
#pragma unroll
    for (int i = 0; i < 4; ++i)
#pragma unroll
        for (int r = 0; r < 4; ++r) {
            int m = i * 16 + fq * 4 + r;
            float mu = s_mu[m], rs = s_rs[m];
#pragma unroll
            for (int j = 0; j < 4; ++j) {
                int n = w * 64 + j * 16 + fr;
                float y = (facc[i][j][r] - mu) * rs * g4[j] + b4[j];
                swz_st(ACT, m, n, y);
            }
        }
    __syncthreads();

    // ---- S3: fw_acc = relu(Fn.W1^T) . W2^T, chained through HB halves
    f32x4 fwacc[4][4] = {};
#pragma unroll
    for (int u = 0; u < 2; ++u) {
        f32x4 hacc[4][4] = {};
        gemm_AB<4>(ACT, W1, u * 512 + w * 64, 1024, 0, fr, fq, hacc);
#pragma unroll
        for (int i = 0; i < 4; ++i)
#pragma unroll
            for (int r = 0; r < 4; ++r) {
                int m = i * 16 + fq * 4 + r;
#pragma unroll
                for (int j = 0; j < 4; ++j) {
                    int n = w * 64 + j * 16 + fr;
                    swz_st(HB, m, n, fmaxf(hacc[i][j][r], 0.f));
                }
            }
        __syncthreads();
        gemm_AB<4>(HB, W2, w * 64, 2048, (size_t)u * 1024, fr, fq, fwacc);
        __syncthreads();
    }

    // ---- S4: sigmoid
#pragma unroll
    for (int i = 0; i < 4; ++i)
#pragma unroll
        for (int j = 0; j < 4; ++j)
#pragma unroll
            for (int r = 0; r < 4; ++r)
                fwacc[i][j][r] = 1.f / (1.f + __expf(-fwacc[i][j][r]));

    // ---- S5: LN2 + multiply by Xc (global re-read, L2-hot) -> Prod into ACT
    ln_reduce(fwacc);
#pragma unroll
    for (int i = 0; i < 4; ++i)
#pragma unroll
        for (int r = 0; r < 4; ++r) {
            int m = i * 16 + fq * 4 + r;
            float mu = s_mu[m], rs = s_rs[m];
            const bf16* xrow = Xc + (size_t)(row0 + m) * L_;
#pragma unroll
            for (int j = 0; j < 4; ++j) {
                int n = w * 64 + j * 16 + fr;
                float y = (fwacc[i][j][r] - mu) * rs * g4[j] + b4[j];
                y *= __bfloat162float(xrow[n]);
                swz_st(ACT, m, n, y);
            }
        }
    __syncthreads();

    // ---- S6: out = Prod . Wl^T  (wave w owns cols w*96..w*96+95), scatter store
    f32x4 oacc[4][6] = {};
    gemm_AB<6>(ACT, Wl, w * 96, 1024, 0, fr, fq, oacc);

    int bb[4][4], cc[4][4];
#pragma unroll
    for (int i = 0; i < 4; ++i)
#pragma unroll
        for (int r = 0; r < 4; ++r) {
            int gm = row0 + i * 16 + fq * 4 + r;
            int b = gm / C_;
            bb[i][r] = b; cc[i][r] = gm - b * C_;
        }
#pragma unroll
    for (int j = 0; j < 6; ++j) {
        int n = w * 96 + j * 16 + fr;
        if (n >= P_) continue;
        float bn = bl[n];
#pragma unroll
        for (int i = 0; i < 4; ++i)
#pragma unroll
            for (int r = 0; r < 4; ++r)
                out[(size_t)bb[i][r] * (P_ * C_) + (size_t)n * C_ + cc[i][r]] =
                    oacc[i][j][r] + bn;
    }
}

extern "C" void kernel_launch(void* const* d_in, const int* in_sizes, int n_in,
                              void* d_out, int out_size, void* d_ws, size_t ws_size,
                              hipStream_t stream) {
    const float* x     = (const float*)d_in[0];
    const float* W1    = (const float*)d_in[1];
    const float* W2    = (const float*)d_in[2];
    const float* gamma = (const float*)d_in[3];
    const float* beta  = (const float*)d_in[4];
    const float* Wl    = (const float*)d_in[5];
    const float* bl    = (const float*)d_in[6];
    float* out = (float*)d_out;

    bf16* ws   = (bf16*)d_ws;
    bf16* Xc   = ws;                           // M_ x 512
    bf16* Dbf  = Xc + (size_t)M_ * L_;         // 512 x 512
    bf16* W1bf = Dbf + (size_t)L_ * L_;        // 1024 x 512
    bf16* W2bf = W1bf + (size_t)H2_ * L_;      // 512 x 1024
    bf16* Wlbf = W2bf + (size_t)L_ * H2_;      // 768 x 512 (zero-padded)

    build_dct<<<(L_ * L_ + 255) / 256, 256, 0, stream>>>(Dbf);
    cvt_bf16<<<(H2_ * L_ + 255) / 256, 256, 0, stream>>>(W1, W1bf, H2_ * L_);
    cvt_bf16<<<(L_ * H2_ + 255) / 256, 256, 0, stream>>>(W2, W2bf, L_ * H2_);
    cvt_wl_pad<<<(PP_ * L_ + 255) / 256, 256, 0, stream>>>(Wl, Wlbf);
    transpose_x<<<dim3((C_ + 31) / 32, (L_ + 31) / 32, B_), 256, 0, stream>>>(x, Xc);

    fused<<<M_ / 64, 512, 0, stream>>>(Xc, Dbf, W1bf, W2bf, Wlbf, gamma, beta, bl, out);
}

// Round 8
// 272.189 us; speedup vs baseline: 1.3951x; 1.3951x over previous
//
#include <hip/hip_runtime.h>
#include <hip/hip_bf16.h>
#include <math.h>

#define B_   32
#define L_   512
#define C_   862
#define P_   720
#define H2_  1024
#define M_   (B_*C_)     // 27584 real rows
#define MP_  27648       // padded to multiple of 256
#define PP_  768         // P padded to multiple of 256

typedef __hip_bfloat16 bf16;
typedef __attribute__((ext_vector_type(8))) short s16x8;
typedef __attribute__((ext_vector_type(4))) float f32x4;

__device__ __forceinline__ void gload_lds16(const bf16* g, bf16* lds) {
    __builtin_amdgcn_global_load_lds(
        (const __attribute__((address_space(1))) void*)g,
        (__attribute__((address_space(3))) void*)lds, 16, 0, 0);
}
__device__ __forceinline__ unsigned short f2b(float f) {
    bf16 h = __float2bfloat16(f);
    return *reinterpret_cast<unsigned short*>(&h);
}
__device__ __forceinline__ float b2f(unsigned short u) {
    return __uint_as_float((unsigned int)u << 16);
}

// ---------------------------------------------------------------- DCT matrix (bf16)
__global__ __launch_bounds__(256) void build_dct(bf16* __restrict__ D) {
    int idx = blockIdx.x * 256 + threadIdx.x;
    if (idx >= L_ * L_) return;
    int k = idx >> 9, l = idx & 511;
    double ang = M_PI * (double)((2 * l + 1) * k) / (2.0 * (double)L_);
    D[idx] = __float2bfloat16((float)(2.0 * cos(ang)));
}

__global__ __launch_bounds__(256) void cvt_bf16(const float* __restrict__ in,
                                                bf16* __restrict__ out, int n) {
    int i = blockIdx.x * 256 + threadIdx.x;
    if (i < n) out[i] = __float2bfloat16(in[i]);
}

// Wl (720,512) -> bf16 padded to (768,512) with zeros
__global__ __launch_bounds__(256) void cvt_wl_pad(const float* __restrict__ in,
                                                  bf16* __restrict__ out) {
    int i = blockIdx.x * 256 + threadIdx.x;
    if (i >= PP_ * L_) return;
    int r = i >> 9;
    out[i] = (r < P_) ? __float2bfloat16(in[i]) : __float2bfloat16(0.f);
}

// ---------------------------------------------------- x (B,L,C) -> Xc (B*C,L) bf16
__global__ __launch_bounds__(256) void transpose_x(const float* __restrict__ x,
                                                   bf16* __restrict__ Xc) {
    __shared__ float tile[32][33];
    int b  = blockIdx.z;
    int c0 = blockIdx.x * 32;
    int l0 = blockIdx.y * 32;
    int tx = threadIdx.x & 31, ty = threadIdx.x >> 5;
#pragma unroll
    for (int i = 0; i < 4; ++i) {
        int l = l0 + ty + i * 8, c = c0 + tx;
        float v = 0.f;
        if (l < L_ && c < C_) v = x[((size_t)b * L_ + l) * C_ + c];
        tile[ty + i * 8][tx] = v;
    }
    __syncthreads();
#pragma unroll
    for (int i = 0; i < 4; ++i) {
        int c = c0 + ty + i * 8, l = l0 + tx;
        if (c < C_ && l < L_)
            Xc[((size_t)b * C_ + c) * L_ + l] = __float2bfloat16(tile[tx][ty + i * 8]);
    }
}

// --------------------- row LayerNorm (512), wave-per-row, bf16 in -> bf16 out
template <bool MUL>
__global__ __launch_bounds__(256) void ln_rows(const bf16* __restrict__ X,
                                               const bf16* __restrict__ Xc,
                                               const float* __restrict__ gamma,
                                               const float* __restrict__ beta,
                                               bf16* __restrict__ Out) {
    int row  = blockIdx.x * 4 + (threadIdx.x >> 6);
    int lane = threadIdx.x & 63;
    const s16x8 v = *reinterpret_cast<const s16x8*>(X + (size_t)row * L_ + lane * 8);
    float f[8], s = 0.f, q = 0.f;
#pragma unroll
    for (int e = 0; e < 8; ++e) {
        f[e] = b2f((unsigned short)v[e]);
        s += f[e]; q += f[e] * f[e];
    }
#pragma unroll
    for (int off = 1; off < 64; off <<= 1) {
        s += __shfl_xor(s, off);
        q += __shfl_xor(q, off);
    }
    float mu = s * (1.f / L_);
    float rs = rsqrtf(q * (1.f / L_) - mu * mu + 1e-6f);
    float4 g0 = *reinterpret_cast<const float4*>(gamma + lane * 8);
    float4 g1 = *reinterpret_cast<const float4*>(gamma + lane * 8 + 4);
    float4 b0 = *reinterpret_cast<const float4*>(beta + lane * 8);
    float4 b1 = *reinterpret_cast<const float4*>(beta + lane * 8 + 4);
    float gg[8] = {g0.x, g0.y, g0.z, g0.w, g1.x, g1.y, g1.z, g1.w};
    float bb[8] = {b0.x, b0.y, b0.z, b0.w, b1.x, b1.y, b1.z, b1.w};
    float xm[8];
    if (MUL) {
        const s16x8 xv = *reinterpret_cast<const s16x8*>(Xc + (size_t)row * L_ + lane * 8);
#pragma unroll
        for (int e = 0; e < 8; ++e) xm[e] = b2f((unsigned short)xv[e]);
    }
    s16x8 o;
#pragma unroll
    for (int e = 0; e < 8; ++e) {
        float y = (f[e] - mu) * rs * gg[e] + bb[e];
        if (MUL) y *= xm[e];
        o[e] = (short)f2b(y);
    }
    *reinterpret_cast<s16x8*>(Out + (size_t)row * L_ + lane * 8) = o;
}

// ------------------------------------------------------ bf16 MFMA NT GEMM, 256x256
// C[m,n] = act( A[m,:] . B[n,:] ).  8 waves (2M x 4N), wave tile 128x64,
// BK=32, TRIPLE-buffered LDS (96 KB), lookahead depth 2, counted vmcnt(8)
// (never drains in-loop), raw s_barrier pair per K-tile (T3/T4).
// LDS read swizzle: granule ^= (row>>1)&3 (2-way residual = free); staged via
// gload_lds with inverse-swizzled SOURCE, linear dest (rule #21).
// OUTMODE 0: bf16 linear [m][ldc] (ACT 0 none / 1 relu / 2 sigmoid)
// OUTMODE 1: f32 scatter out[b][m][c] (n = flat (b,c)) + bias[m]
template <int ACT, int OUTMODE>
__global__ __launch_bounds__(512, 2)
void gemm8(const bf16* __restrict__ A, int lda,
           const bf16* __restrict__ Bm, int ldb,
           const float* __restrict__ bias, void* __restrict__ Cout, int ldc,
           int K, int Mreal, int Nreal) {
    constexpr int BK = 32;
    __shared__ __align__(16) bf16 As[3][256][BK];   // 48 KB
    __shared__ __align__(16) bf16 Bs[3][256][BK];   // 48 KB
    int tid = threadIdx.x, w = tid >> 6, lane = tid & 63;
    int wm = w >> 2, wn = w & 3;
    size_t bm = (size_t)blockIdx.y * 256;
    size_t bn = (size_t)blockIdx.x * 256;
    const bf16* Ab = A + bm * lda;
    const bf16* Bb = Bm + bn * ldb;

    // staging: wave w stages rows [w*16, w*16+16) and [128+w*16, ...) of A and B.
    // lane -> row = lane>>2, linear granule = lane&3; source granule inverse-swizzled.
    int srow = lane >> 2;
    int sgr  = (lane & 3) ^ ((lane >> 3) & 3);   // (lane&3) ^ key(row), key=(row>>1)&3

#define STAGE(bi, kt)                                                                   \
    do {                                                                                \
        int k0_ = (kt) * BK + sgr * 8;                                                  \
        gload_lds16(Ab + (size_t)(w * 16 + srow) * lda + k0_,       &As[bi][w * 16][0]);\
        gload_lds16(Ab + (size_t)(128 + w * 16 + srow) * lda + k0_, &As[bi][128 + w * 16][0]);\
        gload_lds16(Bb + (size_t)(w * 16 + srow) * ldb + k0_,       &Bs[bi][w * 16][0]);\
        gload_lds16(Bb + (size_t)(128 + w * 16 + srow) * ldb + k0_, &Bs[bi][128 + w * 16][0]);\
    } while (0)

    f32x4 acc[8][4] = {};
    int fr = lane & 15, kq = lane >> 4;
    int rsw = (fr >> 1) & 3;                     // read-side swizzle key

    const int NT = K / BK;
    STAGE(0, 0);
    STAGE(1, 1);

    for (int t = 0; t < NT; ++t) {
        int bi = t % 3;
        if (t + 2 < NT) {
            STAGE((t + 2) % 3, t + 2);                          // 4 more in flight
            asm volatile("s_waitcnt vmcnt(8)" ::: "memory");    // tile t landed
        } else if (t + 1 < NT) {
            asm volatile("s_waitcnt vmcnt(4)" ::: "memory");
        } else {
            asm volatile("s_waitcnt vmcnt(0)" ::: "memory");
        }
        __builtin_amdgcn_s_barrier();            // tile t visible to all waves

        const char* Ap = (const char*)&As[bi][0][0];
        const char* Bp = (const char*)&Bs[bi][0][0];
        s16x8 av[8], bv[4];
#pragma unroll
        for (int i = 0; i < 8; ++i) {
            int row = wm * 128 + i * 16 + fr;
            av[i] = *reinterpret_cast<const s16x8*>(Ap + row * 64 + ((kq ^ rsw) << 4));
        }
#pragma unroll
        for (int j = 0; j < 4; ++j) {
            int row = wn * 64 + j * 16 + fr;
            bv[j] = *reinterpret_cast<const s16x8*>(Bp + row * 64 + ((kq ^ rsw) << 4));
        }
#pragma unroll
        for (int i = 0; i < 8; ++i)
#pragma unroll
            for (int j = 0; j < 4; ++j)
                acc[i][j] = __builtin_amdgcn_mfma_f32_16x16x32_bf16(av[i], bv[j], acc[i][j], 0, 0, 0);

        __builtin_amdgcn_s_barrier();            // all waves done reading buf bi
    }
#undef STAGE

    int fq = lane >> 4;
    if (OUTMODE == 0) {
        bf16* C = (bf16*)Cout;
#pragma unroll
        for (int i = 0; i < 8; ++i) {
#pragma unroll
            for (int r = 0; r < 4; ++r) {
                int m = (int)bm + wm * 128 + i * 16 + fq * 4 + r;
                if (m >= Mreal) continue;
#pragma unroll
                for (int j = 0; j < 4; ++j) {
                    int n = (int)bn + wn * 64 + j * 16 + fr;
                    if (n >= Nreal) continue;
                    float v = acc[i][j][r];
                    if (ACT == 1) v = fmaxf(v, 0.f);
                    if (ACT == 2) v = 1.f / (1.f + __expf(-v));
                    C[(size_t)m * ldc + n] = __float2bfloat16(v);
                }
            }
        }
    } else {
        float* O = (float*)Cout;
#pragma unroll
        for (int j = 0; j < 4; ++j) {
            int n = (int)bn + wn * 64 + j * 16 + fr;
            if (n >= Nreal) continue;
            int sb = n / C_, sc = n - sb * C_;
#pragma unroll
            for (int i = 0; i < 8; ++i) {
#pragma unroll
                for (int r = 0; r < 4; ++r) {
                    int m = (int)bm + wm * 128 + i * 16 + fq * 4 + r;
                    if (m >= Mreal) continue;
                    O[(size_t)sb * (P_ * C_) + (size_t)m * C_ + sc] = acc[i][j][r] + bias[m];
                }
            }
        }
    }
}

extern "C" void kernel_launch(void* const* d_in, const int* in_sizes, int n_in,
                              void* d_out, int out_size, void* d_ws, size_t ws_size,
                              hipStream_t stream) {
    const float* x     = (const float*)d_in[0];
    const float* W1    = (const float*)d_in[1];
    const float* W2    = (const float*)d_in[2];
    const float* gamma = (const float*)d_in[3];
    const float* beta  = (const float*)d_in[4];
    const float* Wl    = (const float*)d_in[5];
    const float* bl    = (const float*)d_in[6];
    float* out = (float*)d_out;

    bf16* ws   = (bf16*)d_ws;
    bf16* Xc   = ws;                           // MP_ x 512
    bf16* Fq   = Xc + (size_t)MP_ * L_;        // MP_ x 512 (freq, later fw)
    bf16* Fn   = Fq + (size_t)MP_ * L_;        // MP_ x 512 (Fn, later Prod)
    bf16* Hb   = Fn + (size_t)MP_ * L_;        // MP_ x 1024
    bf16* Dbf  = Hb + (size_t)MP_ * H2_;       // 512 x 512
    bf16* W1bf = Dbf + (size_t)L_ * L_;        // 1024 x 512
    bf16* W2bf = W1bf + (size_t)H2_ * L_;      // 512 x 1024
    bf16* Wlbf = W2bf + (size_t)L_ * H2_;      // 768 x 512 (zero-padded)

    build_dct<<<(L_ * L_ + 255) / 256, 256, 0, stream>>>(Dbf);
    cvt_bf16<<<(H2_ * L_ + 255) / 256, 256, 0, stream>>>(W1, W1bf, H2_ * L_);
    cvt_bf16<<<(L_ * H2_ + 255) / 256, 256, 0, stream>>>(W2, W2bf, L_ * H2_);
    cvt_wl_pad<<<(PP_ * L_ + 255) / 256, 256, 0, stream>>>(Wl, Wlbf);
    transpose_x<<<dim3((C_ + 31) / 32, (L_ + 31) / 32, B_), 256, 0, stream>>>(x, Xc);

    // Stage A: freq = Xc . D^T  (bf16 out)   grid 2 x 108
    gemm8<0, 0><<<dim3(L_ / 256, MP_ / 256), 512, 0, stream>>>(
        Xc, L_, Dbf, L_, nullptr, Fq, L_, L_, M_, L_);
    ln_rows<false><<<M_ / 4, 256, 0, stream>>>(Fq, nullptr, gamma, beta, Fn);

    // Stage B: H = relu(Fn . W1^T)  (bf16 out)   grid 4 x 108
    gemm8<1, 0><<<dim3(H2_ / 256, MP_ / 256), 512, 0, stream>>>(
        Fn, L_, W1bf, L_, nullptr, Hb, H2_, L_, M_, H2_);

    // Stage C: fw = sigmoid(H . W2^T)  (bf16 out, K=1024)   grid 2 x 108
    gemm8<2, 0><<<dim3(L_ / 256, MP_ / 256), 512, 0, stream>>>(
        Hb, H2_, W2bf, H2_, nullptr, Fq, L_, H2_, M_, L_);
    // Prod = LN(fw) * Xc
    ln_rows<true><<<M_ / 4, 256, 0, stream>>>(Fq, Xc, gamma, beta, Fn);

    // Stage D (operand-swapped for coalesced scatter): out[b,p,c] = Wl[p,:].Prod[(b,c),:] + bl[p]
    // grid 108 x 3:  M = PP_ (Wl rows), N = MP_ (flat (b,c))
    gemm8<0, 1><<<dim3(MP_ / 256, PP_ / 256), 512, 0, stream>>>(
        Wlbf, L_, Fn, L_, bl, out, 0, L_, P_, M_);
}